// Round 9
// baseline (34.018 us; speedup 1.0000x reference)
//
#include <hip/hip_runtime.h>
#include <hip/hip_bf16.h>
#include <math.h>

#define B 2
#define T 4096
#define H 8
#define E 64
#define D 64
#define C 128          // chunk length
#define NC (T / C)     // 32 chunks
#define BH (B * H)     // 16
#define EPS 1e-6f
#define PT 132         // bf16 row stride for k1 transposed tiles
#define PQ 72          // bf16 row stride sQ / phiK (144B, 16B-aligned)
#define PV 136         // bf16 row stride V^T in sKB (272B, 16B-aligned)

typedef short short8 __attribute__((ext_vector_type(8)));
typedef float f32x4 __attribute__((ext_vector_type(4)));

__device__ __forceinline__ float phi(float x) {
    return x > 0.0f ? x + 1.0f : __expf(x);
}
__device__ __forceinline__ uint pk2(float a, float b) {   // 2xf32 -> packed bf16 (RNE)
    __hip_bfloat162 h = __float22bfloat162_rn(make_float2(a, b));
    union { __hip_bfloat162 h2; uint u; } cv; cv.h2 = h; return cv.u;
}
__device__ __forceinline__ ushort f2bf(float f) {
    uint u = __float_as_uint(f);
    return (ushort)((u + 0x7FFFu + ((u >> 16) & 1u)) >> 16);
}
__device__ __forceinline__ float bf2f(ushort h) {
    return __uint_as_float(((uint)h) << 16);
}

// ---------------- Kernel 1: per-chunk partials via MFMA (R7, unchanged) -----
__global__ __launch_bounds__(256) void k_chunk_sums(
        const float* __restrict__ Kg, const float* __restrict__ Vg,
        ushort* __restrict__ SpartBf, float* __restrict__ zpart,
        ushort* __restrict__ VTg, ushort* __restrict__ PKg) {
    int blk = blockIdx.x;
    int bh = blk / NC, c = blk % NC;
    int b = bh / H, h = bh % H;
    int t0 = c * C;
    __shared__ ushort sKt[E][PT];   // phiK^T [e][t]
    __shared__ ushort sVt[D][PT];   // V^T    [d][t]
    int tid = threadIdx.x;
    int lane = tid & 63, w = tid >> 6;
    const float4* Kg4 = (const float4*)Kg;
    const float4* Vg4 = (const float4*)Vg;
    uint2* PK2 = (uint2*)(PKg + (size_t)blk * (C * E));

    for (int l = tid; l < (C / 2) * 16; l += 256) {   // 4 iters
        int i2 = l >> 4, e4 = l & 15;
        int t = i2 * 2;
        size_t g0 = ((size_t)(b * T + t0 + t) * H + h) * 16 + e4;
        size_t g1 = g0 + H * 16;                      // next t row
        float4 ka = Kg4[g0], kb = Kg4[g1];
        float4 va = Vg4[g0], vb = Vg4[g1];
        float pk0[4] = {phi(ka.x), phi(ka.y), phi(ka.z), phi(ka.w)};
        float pk1[4] = {phi(kb.x), phi(kb.y), phi(kb.z), phi(kb.w)};
        float pv0[4] = {va.x, va.y, va.z, va.w};
        float pv1[4] = {vb.x, vb.y, vb.z, vb.w};
        #pragma unroll
        for (int cc = 0; cc < 4; ++cc) {              // t-paired uint stores
            *(uint*)&sKt[e4 * 4 + cc][t] = pk2(pk0[cc], pk1[cc]);
            *(uint*)&sVt[e4 * 4 + cc][t] = pk2(pv0[cc], pv1[cc]);
        }
        PK2[t * 16 + e4]       = make_uint2(pk2(pk0[0], pk0[1]), pk2(pk0[2], pk0[3]));
        PK2[(t + 1) * 16 + e4] = make_uint2(pk2(pk1[0], pk1[1]), pk2(pk1[2], pk1[3]));
    }
    __syncthreads();

    // S^T: D[m=e][n=d] = sum_t phiK^T[e][t] V^T[d][t]; wave w owns e-tile w
    {
        int g = lane >> 4, cl = lane & 15;
        int mt = w;
        f32x4 acc[4] = {};
        for (int ks = 0; ks < 4; ++ks) {
            short8 a = *(const short8*)&sKt[mt * 16 + cl][ks * 32 + g * 8];
            #pragma unroll
            for (int nt = 0; nt < 4; ++nt) {
                short8 bb = *(const short8*)&sVt[nt * 16 + cl][ks * 32 + g * 8];
                acc[nt] = __builtin_amdgcn_mfma_f32_16x16x32_bf16(a, bb, acc[nt], 0, 0, 0);
            }
        }
        ushort* Sp = SpartBf + (size_t)blk * (E * D);
        #pragma unroll
        for (int nt = 0; nt < 4; ++nt) {
            int d = nt * 16 + cl;
            *(uint2*)&Sp[d * E + mt * 16 + g * 4] =
                make_uint2(pk2(acc[nt][0], acc[nt][1]), pk2(acc[nt][2], acc[nt][3]));
        }
    }
    // stage V^T bf16 to global
    ushort* vt = VTg + (size_t)blk * (C * D);
    for (int l = tid; l < C * D / 8; l += 256)
        *(short8*)&vt[(l >> 4) * C + (l & 15) * 8] = *(const short8*)&sVt[l >> 4][(l & 15) * 8];
    if (tid < E) {
        float s = 0.0f;
        #pragma unroll
        for (int p = 0; p < 16; ++p) {
            short8 v = *(const short8*)&sKt[tid][p * 8];
            #pragma unroll
            for (int j = 0; j < 8; ++j) s += bf2f((ushort)v[j]);
        }
        zpart[(size_t)blk * E + tid] = s;
    }
}

// ---------------- Kernel 2: exclusive prefix scan (R7, unchanged) -----------
__global__ __launch_bounds__(256) void k_scan(
        const ushort* __restrict__ SpartBf, float* __restrict__ zpart,
        ushort* __restrict__ S0bf) {
    int bh  = blockIdx.x / 17;
    int sub = blockIdx.x % 17;
    int tid = threadIdx.x;
    if (sub < 16) {
        int l = sub * 256 + tid;
        const ushort* base = SpartBf + (size_t)bh * NC * (E * D) + l;
        ushort* obase = S0bf + (size_t)bh * NC * (E * D) + l;
        float vals[NC];
        #pragma unroll
        for (int c = 0; c < NC; ++c) vals[c] = bf2f(base[(size_t)c * (E * D)]);
        float run = 0.0f;
        #pragma unroll
        for (int c = 0; c < NC; ++c) {
            obase[(size_t)c * (E * D)] = f2bf(run);
            run += vals[c];
        }
    } else if (tid < E) {
        float* base = zpart + (size_t)bh * NC * E + tid;
        float vals[NC];
        #pragma unroll
        for (int c = 0; c < NC; ++c) vals[c] = base[(size_t)c * E];
        float run = 0.0f;
        #pragma unroll
        for (int c = 0; c < NC; ++c) {
            base[(size_t)c * E] = run;
            run += vals[c];
        }
    }
}

// ---------------- Kernel 3: per-chunk output via MFMA (restructured) --------
// Phase B: S = phiQ @ phiK^T (causal, bf16, swizzled)  +  tail O += phiQ@S0^T,
//          den += z.phiQ  (S0/z as per-lane register A-fragments)
// Phase D: O += V^T-rows (A) x S-rows (B)  -> lane holds 4 consecutive cols
//          den += ones x S  (every acc reg == den(row): no shuffle)
__global__ __launch_bounds__(512, 4) void k_output(
        const float* __restrict__ Qg, const ushort* __restrict__ PKg,
        const ushort* __restrict__ VTg, const ushort* __restrict__ S0bf,
        const float* __restrict__ zpart, float* __restrict__ Og) {
    int blk = blockIdx.x;
    int bh = blk / NC, c = blk % NC;
    int b = bh / H, h = bh % H;
    int t0 = c * C;

    __shared__ ushort sQ[C][PQ];        // phi(Q) bf16                 18432 B
    __shared__ ushort sKB[9216];        // phiK[128][PQ] -> V^T[64][PV] 18432 B
    __shared__ ushort sA[C][C];         // scores, XOR-swizzled         32768 B

    int tid = threadIdx.x;
    int lane = tid & 63;
    int w = tid >> 6;
    int g = lane >> 4, cl = lane & 15;

    const int permv[8] = {0, 1, 2, 3, 6, 7, 4, 5};
    int rt = permv[w];                  // this wave's output row-tile
    int arow = rt * 16 + cl;

    const float4* Qg4 = (const float4*)Qg;

    // ---- phase A: loads ----
    for (int l = tid; l < C * 8; l += 512) {        // 2 iters: phi(Q)->LDS
        int i = l >> 3, e8 = l & 7;
        size_t gg = ((size_t)(b * T + t0 + i) * H + h) * 16 + e8 * 2;
        float4 qa = Qg4[gg], qb = Qg4[gg + 1];
        uint4 qv = make_uint4(pk2(phi(qa.x), phi(qa.y)), pk2(phi(qa.z), phi(qa.w)),
                              pk2(phi(qb.x), phi(qb.y)), pk2(phi(qb.z), phi(qb.w)));
        *(uint4*)&sQ[i][e8 * 8] = qv;
    }
    const short8* pk8 = (const short8*)(PKg + (size_t)blk * (C * E));
    for (int l = tid; l < C * 8; l += 512)          // phiK bf16 straight in
        *(short8*)&sKB[(l >> 3) * PQ + (l & 7) * 8] = pk8[l];
    {   // pre-zero sA
        uint4 zz = make_uint4(0, 0, 0, 0);
        ushort* af = (ushort*)sA;
        #pragma unroll
        for (int it = 0; it < 4; ++it)
            *(uint4*)&af[(tid + 512 * it) * 8] = zz;
    }
    // V^T -> regs (for phase C)
    const short8* vt8 = (const short8*)(VTg + (size_t)blk * (C * D));
    short8 vt0 = vt8[tid * 2], vt1 = vt8[tid * 2 + 1];
    // S0^T per-lane A-fragments: s0f[nt][s2] = S0T[nt*16+cl][s2*32+g*8 ..+7]
    const ushort* S0p = S0bf + (size_t)blk * (E * D);
    short8 s0f[4][2];
    #pragma unroll
    for (int nt = 0; nt < 4; ++nt)
        #pragma unroll
        for (int s2 = 0; s2 < 2; ++s2)
            s0f[nt][s2] = *(const short8*)&S0p[(nt * 16 + cl) * E + s2 * 32 + g * 8];
    // z broadcast A-fragments (same for all cl)
    const float* zp = zpart + (size_t)blk * E;
    short8 zf[2];
    #pragma unroll
    for (int s2 = 0; s2 < 2; ++s2) {
        int e0 = s2 * 32 + g * 8;
        float4 za = *(const float4*)&zp[e0];
        float4 zb = *(const float4*)&zp[e0 + 4];
        uint4 zu = make_uint4(pk2(za.x, za.y), pk2(za.z, za.w),
                              pk2(zb.x, zb.y), pk2(zb.z, zb.w));
        zf[s2] = *(short8*)&zu;
    }
    __syncthreads();

    f32x4 acc[5] = {};   // 4 col-tiles + den, live across B..D

    // ---- phase B: scores (lower-triangle tiles) + register-S0 tail ----
    for (int idx = w; idx < 36; idx += 8) {
        int tr = 0;
        while ((tr + 1) * (tr + 2) / 2 <= idx) ++tr;
        int tc = idx - tr * (tr + 1) / 2;
        f32x4 sacc = {};
        #pragma unroll
        for (int ks = 0; ks < 2; ++ks) {
            short8 a  = *(const short8*)&sKB[(tc * 16 + cl) * PQ + ks * 32 + g * 8];
            short8 bq = *(const short8*)&sQ[tr * 16 + cl][ks * 32 + g * 8];
            sacc = __builtin_amdgcn_mfma_f32_16x16x32_bf16(a, bq, sacc, 0, 0, 0);
        }
        int iq = tr * 16 + cl;                  // query row (n)
        int j0 = tc * 16 + g * 4;               // key cols (m), 4 consecutive
        float v0 = (j0 + 0 <= iq) ? sacc[0] : 0.0f;
        float v1 = (j0 + 1 <= iq) ? sacc[1] : 0.0f;
        float v2 = (j0 + 2 <= iq) ? sacc[2] : 0.0f;
        float v3 = (j0 + 3 <= iq) ? sacc[3] : 0.0f;
        int pb = (tc * 2 + (g >> 1)) ^ (iq & 7);
        *(uint2*)&sA[iq][pb * 8 + (g & 1) * 4] = make_uint2(pk2(v0, v1), pk2(v2, v3));
    }
    // tail: O += phiQ @ S0^T ; den += z . phiQ   (swapped orientation)
    #pragma unroll
    for (int s2 = 0; s2 < 2; ++s2) {
        short8 bq = *(const short8*)&sQ[arow][s2 * 32 + g * 8];
        #pragma unroll
        for (int nt = 0; nt < 4; ++nt)
            acc[nt] = __builtin_amdgcn_mfma_f32_16x16x32_bf16(s0f[nt][s2], bq, acc[nt], 0, 0, 0);
        acc[4] = __builtin_amdgcn_mfma_f32_16x16x32_bf16(zf[s2], bq, acc[4], 0, 0, 0);
    }
    __syncthreads();

    // ---- phase C: V^T rows into sKB (phiK dead) ----
    {
        int i0 = tid * 2, i1 = tid * 2 + 1;      // over [64][16] short8 grid
        *(short8*)&sKB[(i0 >> 4) * PV + (i0 & 15) * 8] = vt0;
        *(short8*)&sKB[(i1 >> 4) * PV + (i1 & 15) * 8] = vt1;
    }
    __syncthreads();

    // ---- phase D: O += V^T x S ; den += ones x S ----
    {
        const short8 ones = {16256, 16256, 16256, 16256, 16256, 16256, 16256, 16256};
        int aswz = arow & 7;
        int smax = (rt * 16 + 15) >> 5;          // skip all-zero causal K-steps
        for (int s = 0; s <= smax; ++s) {
            short8 bs = *(const short8*)&sA[arow][(((s * 4 + g) ^ aswz)) * 8];
            #pragma unroll
            for (int nt = 0; nt < 4; ++nt) {
                short8 a = *(const short8*)&sKB[(nt * 16 + cl) * PV + s * 32 + g * 8];
                acc[nt] = __builtin_amdgcn_mfma_f32_16x16x32_bf16(a, bs, acc[nt], 0, 0, 0);
            }
            acc[4] = __builtin_amdgcn_mfma_f32_16x16x32_bf16(ones, bs, acc[4], 0, 0, 0);
        }
        // store: lane owns row rt*16+cl, cols nt*16 + g*4 + {0..3}
        int row = rt * 16 + cl;
        float den = acc[4][0];                   // all regs equal den(row)
        float zi = 1.0f / (den + EPS);
        size_t ga = ((size_t)(b * T + t0 + row) * H + h) * 64;
        #pragma unroll
        for (int nt = 0; nt < 4; ++nt) {
            float4 o = make_float4(acc[nt][0] * zi, acc[nt][1] * zi,
                                   acc[nt][2] * zi, acc[nt][3] * zi);
            *(float4*)&Og[ga + nt * 16 + g * 4] = o;
        }
    }
}

extern "C" void kernel_launch(void* const* d_in, const int* in_sizes, int n_in,
                              void* d_out, int out_size, void* d_ws, size_t ws_size,
                              hipStream_t stream) {
    const float* q = (const float*)d_in[0];
    const float* k = (const float*)d_in[1];
    const float* v = (const float*)d_in[2];
    float* out = (float*)d_out;

    ushort* SpartBf = (ushort*)d_ws;                                // 4.2 MB
    float*  zpart   = (float*)(SpartBf + (size_t)BH * NC * E * D);  // 128 KB
    ushort* VTg     = (ushort*)(zpart + (size_t)BH * NC * E);       // 8.4 MB
    ushort* PKg     = VTg + (size_t)BH * NC * C * D;                // 8.4 MB
    ushort* S0bf    = PKg + (size_t)BH * NC * C * E;                // 4.2 MB

    k_chunk_sums<<<BH * NC, 256, 0, stream>>>(k, v, SpartBf, zpart, VTg, PKg);
    k_scan<<<BH * 17, 256, 0, stream>>>(SpartBf, zpart, S0bf);
    k_output<<<BH * NC, 512, 0, stream>>>(q, PKg, VTg, S0bf, zpart, out);
}

// Round 10
// 31.537 us; speedup vs baseline: 1.0787x; 1.0787x over previous
//
#include <hip/hip_runtime.h>
#include <hip/hip_bf16.h>
#include <math.h>

#define B 2
#define T 4096
#define H 8
#define E 64
#define D 64
#define C 128          // chunk length
#define NC (T / C)     // 32 chunks
#define BH (B * H)     // 16
#define EPS 1e-6f
#define PT 132         // bf16 row stride for k1 transposed tiles
#define PQ 72          // bf16 row stride sQ / phiK in sKB (144B, 16B-aligned)
#define PBT 200        // bf16 row stride Bt (400B, 16B-aligned)

typedef short short8 __attribute__((ext_vector_type(8)));
typedef float f32x4 __attribute__((ext_vector_type(4)));

__device__ __forceinline__ float phi(float x) {
    return x > 0.0f ? x + 1.0f : __expf(x);
}
__device__ __forceinline__ uint pk2(float a, float b) {   // 2xf32 -> packed bf16 (RNE)
    __hip_bfloat162 h = __float22bfloat162_rn(make_float2(a, b));
    union { __hip_bfloat162 h2; uint u; } cv; cv.h2 = h; return cv.u;
}
__device__ __forceinline__ ushort f2bf(float f) {
    uint u = __float_as_uint(f);
    return (ushort)((u + 0x7FFFu + ((u >> 16) & 1u)) >> 16);
}
__device__ __forceinline__ float bf2f(ushort h) {
    return __uint_as_float(((uint)h) << 16);
}

// ---------------- Kernel 1: per-chunk partials via MFMA (512 threads) -------
// SpartBf[blk][d][e] = bf16( sum_t phiK[t][e] * V[t][d] )
// VTg[blk][d][t] bf16 V^T ; PKg[blk][t][e] bf16 phiK ; zpart[blk][e] colsum f32
__global__ __launch_bounds__(512) void k_chunk_sums(
        const float* __restrict__ Kg, const float* __restrict__ Vg,
        ushort* __restrict__ SpartBf, float* __restrict__ zpart,
        ushort* __restrict__ VTg, ushort* __restrict__ PKg) {
    int blk = blockIdx.x;
    int bh = blk / NC, c = blk % NC;
    int b = bh / H, h = bh % H;
    int t0 = c * C;
    __shared__ ushort sKt[E][PT];   // phiK^T [e][t]
    __shared__ ushort sVt[D][PT];   // V^T    [d][t]
    int tid = threadIdx.x;
    int lane = tid & 63, w = tid >> 6;
    int g = lane >> 4, cl = lane & 15;
    const float4* Kg4 = (const float4*)Kg;
    const float4* Vg4 = (const float4*)Vg;
    uint2* PK2 = (uint2*)(PKg + (size_t)blk * (C * E));

    for (int l = tid; l < (C / 2) * 16; l += 512) {   // 2 iters
        int i2 = l >> 4, e4 = l & 15;
        int t = i2 * 2;
        size_t g0 = ((size_t)(b * T + t0 + t) * H + h) * 16 + e4;
        size_t g1 = g0 + H * 16;                      // next t row
        float4 ka = Kg4[g0], kb = Kg4[g1];
        float4 va = Vg4[g0], vb = Vg4[g1];
        float pk0[4] = {phi(ka.x), phi(ka.y), phi(ka.z), phi(ka.w)};
        float pk1[4] = {phi(kb.x), phi(kb.y), phi(kb.z), phi(kb.w)};
        float pv0[4] = {va.x, va.y, va.z, va.w};
        float pv1[4] = {vb.x, vb.y, vb.z, vb.w};
        #pragma unroll
        for (int cc = 0; cc < 4; ++cc) {              // t-paired uint stores
            *(uint*)&sKt[e4 * 4 + cc][t] = pk2(pk0[cc], pk1[cc]);
            *(uint*)&sVt[e4 * 4 + cc][t] = pk2(pv0[cc], pv1[cc]);
        }
        PK2[t * 16 + e4]       = make_uint2(pk2(pk0[0], pk0[1]), pk2(pk0[2], pk0[3]));
        PK2[(t + 1) * 16 + e4] = make_uint2(pk2(pk1[0], pk1[1]), pk2(pk1[2], pk1[3]));
    }
    __syncthreads();

    // S^T: D[m=e][n=d]; 16 tiles over 8 waves: mt = w>>1, nt = (w&1)*2 + u
    {
        int mt = w >> 1;
        f32x4 acc[2] = {};
        for (int ks = 0; ks < 4; ++ks) {
            short8 a = *(const short8*)&sKt[mt * 16 + cl][ks * 32 + g * 8];
            #pragma unroll
            for (int u = 0; u < 2; ++u) {
                int nt = (w & 1) * 2 + u;
                short8 bb = *(const short8*)&sVt[nt * 16 + cl][ks * 32 + g * 8];
                acc[u] = __builtin_amdgcn_mfma_f32_16x16x32_bf16(a, bb, acc[u], 0, 0, 0);
            }
        }
        ushort* Sp = SpartBf + (size_t)blk * (E * D);
        #pragma unroll
        for (int u = 0; u < 2; ++u) {
            int d = ((w & 1) * 2 + u) * 16 + cl;
            *(uint2*)&Sp[d * E + mt * 16 + g * 4] =
                make_uint2(pk2(acc[u][0], acc[u][1]), pk2(acc[u][2], acc[u][3]));
        }
    }
    // stage V^T bf16 to global
    ushort* vt = VTg + (size_t)blk * (C * D);
    for (int l = tid; l < C * D / 8; l += 512)        // 2 iters
        *(short8*)&vt[(l >> 4) * C + (l & 15) * 8] = *(const short8*)&sVt[l >> 4][(l & 15) * 8];
    if (tid < E) {
        float s = 0.0f;
        #pragma unroll
        for (int p = 0; p < 16; ++p) {
            short8 v = *(const short8*)&sKt[tid][p * 8];
            #pragma unroll
            for (int j = 0; j < 8; ++j) s += bf2f((ushort)v[j]);
        }
        zpart[(size_t)blk * E + tid] = s;
    }
}

// ---------------- Kernel 2: exclusive prefix scan (bf16 in, bf16 out) -------
__global__ __launch_bounds__(256) void k_scan(
        const ushort* __restrict__ SpartBf, float* __restrict__ zpart,
        ushort* __restrict__ S0bf) {
    int bh  = blockIdx.x / 17;
    int sub = blockIdx.x % 17;
    int tid = threadIdx.x;
    if (sub < 16) {
        int l = sub * 256 + tid;
        const ushort* base = SpartBf + (size_t)bh * NC * (E * D) + l;
        ushort* obase = S0bf + (size_t)bh * NC * (E * D) + l;
        float vals[NC];
        #pragma unroll
        for (int c = 0; c < NC; ++c) vals[c] = bf2f(base[(size_t)c * (E * D)]);
        float run = 0.0f;
        #pragma unroll
        for (int c = 0; c < NC; ++c) {
            obase[(size_t)c * (E * D)] = f2bf(run);
            run += vals[c];
        }
    } else if (tid < E) {
        float* base = zpart + (size_t)bh * NC * E + tid;
        float vals[NC];
        #pragma unroll
        for (int c = 0; c < NC; ++c) vals[c] = base[(size_t)c * E];
        float run = 0.0f;
        #pragma unroll
        for (int c = 0; c < NC; ++c) {
            base[(size_t)c * E] = run;
            run += vals[c];
        }
    }
}

// ---------------- Kernel 3: per-chunk output via MFMA (R7 structure) --------
// S = phiQ @ phiK^T (causal, bf16, XOR-swizzled)
// [O | den] = [S | phiQ] @ [V ; S0 | ones ; z]   (den from 5th n-tile)
__global__ __launch_bounds__(512, 4) void k_output(
        const float* __restrict__ Qg, const ushort* __restrict__ PKg,
        const ushort* __restrict__ VTg, const ushort* __restrict__ S0bf,
        const float* __restrict__ zpart, float* __restrict__ Og) {
    int blk = blockIdx.x;
    int bh = blk / NC, c = blk % NC;
    int b = bh / H, h = bh % H;
    int t0 = c * C;

    __shared__ ushort sQ[C][PQ];        // phi(Q) bf16                 18432 B
    __shared__ ushort sKB[13000];       // phiK[128][PQ] -> Bt[65][PBT] 26000 B
    __shared__ ushort sA[C][C];         // scores, XOR-swizzled         32768 B

    int tid = threadIdx.x;
    int lane = tid & 63;
    int w = tid >> 6;
    int g = lane >> 4, cl = lane & 15;

    const float4* Qg4 = (const float4*)Qg;

    // ---- phase A ----
    for (int l = tid; l < C * 8; l += 512) {        // 2 iters: phi(Q)->LDS
        int i = l >> 3, e8 = l & 7;
        size_t gg = ((size_t)(b * T + t0 + i) * H + h) * 16 + e8 * 2;
        float4 qa = Qg4[gg], qb = Qg4[gg + 1];
        uint4 qv = make_uint4(pk2(phi(qa.x), phi(qa.y)), pk2(phi(qa.z), phi(qa.w)),
                              pk2(phi(qb.x), phi(qb.y)), pk2(phi(qb.z), phi(qb.w)));
        *(uint4*)&sQ[i][e8 * 8] = qv;
    }
    const short8* pk8 = (const short8*)(PKg + (size_t)blk * (C * E));
    for (int l = tid; l < C * 8; l += 512)          // phiK bf16 straight in
        *(short8*)&sKB[(l >> 3) * PQ + (l & 7) * 8] = pk8[l];
    {   // pre-zero sA
        uint4 zz = make_uint4(0, 0, 0, 0);
        ushort* af = (ushort*)sA;
        #pragma unroll
        for (int it = 0; it < 4; ++it)
            *(uint4*)&af[(tid + 512 * it) * 8] = zz;
    }
    const short8* vt8 = (const short8*)(VTg + (size_t)blk * (C * D));
    short8 vt0 = vt8[tid * 2], vt1 = vt8[tid * 2 + 1];
    short8 s0reg = ((const short8*)(S0bf + (size_t)blk * (E * D)))[tid];
    float zreg = (tid < E) ? zpart[(size_t)blk * E + tid] : 0.0f;
    __syncthreads();

    // ---- phase B: scores, lower-triangle tiles; lookup (tr,tc) ----
    {
        static const unsigned char TRT[36] = {0,1,1,2,2,2,3,3,3,3,4,4,4,4,4,
                                              5,5,5,5,5,5,6,6,6,6,6,6,6,
                                              7,7,7,7,7,7,7,7};
        static const unsigned char TCT[36] = {0,0,1,0,1,2,0,1,2,3,0,1,2,3,4,
                                              0,1,2,3,4,5,0,1,2,3,4,5,6,
                                              0,1,2,3,4,5,6,7};
        for (int idx = w; idx < 36; idx += 8) {
            int tr = TRT[idx], tc = TCT[idx];
            f32x4 acc = {};
            #pragma unroll
            for (int ks = 0; ks < 2; ++ks) {
                short8 a  = *(const short8*)&sKB[(tc * 16 + cl) * PQ + ks * 32 + g * 8];
                short8 bq = *(const short8*)&sQ[tr * 16 + cl][ks * 32 + g * 8];
                acc = __builtin_amdgcn_mfma_f32_16x16x32_bf16(a, bq, acc, 0, 0, 0);
            }
            int iq = tr * 16 + cl;              // query row (n)
            int j0 = tc * 16 + g * 4;           // key cols (m), 4 consecutive
            float v0 = (j0 + 0 <= iq) ? acc[0] : 0.0f;
            float v1 = (j0 + 1 <= iq) ? acc[1] : 0.0f;
            float v2 = (j0 + 2 <= iq) ? acc[2] : 0.0f;
            float v3 = (j0 + 3 <= iq) ? acc[3] : 0.0f;
            int pb = (tc * 2 + (g >> 1)) ^ (iq & 7);
            *(uint2*)&sA[iq][pb * 8 + (g & 1) * 4] = make_uint2(pk2(v0, v1), pk2(v2, v3));
        }
    }
    __syncthreads();

    // ---- phase C: Bt = [V^T | S0 ; ones | z] rows in sKB ----
    {
        int i0 = tid * 2, i1 = tid * 2 + 1;      // over [64][16] short8 grid
        *(short8*)&sKB[(i0 >> 4) * PBT + (i0 & 15) * 8] = vt0;
        *(short8*)&sKB[(i1 >> 4) * PBT + (i1 & 15) * 8] = vt1;
        *(short8*)&sKB[(tid >> 3) * PBT + 128 + (tid & 7) * 8] = s0reg;
        if (tid < E) sKB[64 * PBT + 128 + tid] = f2bf(zreg);
        else if (tid < E + 16) {
            short8 ones = {16256, 16256, 16256, 16256, 16256, 16256, 16256, 16256};
            *(short8*)&sKB[64 * PBT + (tid - E) * 8] = ones;
        }
    }
    __syncthreads();

    // ---- phase D: [O|den] = [S|phiQ] @ Bt; wave w owns m-tile perm[w] ----
    {
        const int permv[8] = {0, 1, 2, 3, 6, 7, 4, 5};
        int mt = permv[w];
        int m0 = mt * 16;
        int arow = m0 + cl;
        int aswz = arow & 7;
        int smax = (m0 + 15) >> 5;
        f32x4 acc[5] = {};
        for (int s = 0; s <= smax; ++s) {
            short8 a = *(const short8*)&sA[arow][(((s * 4 + g) ^ aswz)) * 8];
            #pragma unroll
            for (int nt = 0; nt < 5; ++nt) {
                short8 bb = *(const short8*)&sKB[(nt * 16 + cl) * PBT + s * 32 + g * 8];
                acc[nt] = __builtin_amdgcn_mfma_f32_16x16x32_bf16(a, bb, acc[nt], 0, 0, 0);
            }
        }
        #pragma unroll
        for (int s2 = 0; s2 < 2; ++s2) {
            short8 a = *(const short8*)&sQ[arow][s2 * 32 + g * 8];
            #pragma unroll
            for (int nt = 0; nt < 5; ++nt) {
                short8 bb = *(const short8*)&sKB[(nt * 16 + cl) * PBT + 128 + s2 * 32 + g * 8];
                acc[nt] = __builtin_amdgcn_mfma_f32_16x16x32_bf16(a, bb, acc[nt], 0, 0, 0);
            }
        }
        #pragma unroll
        for (int r = 0; r < 4; ++r) {
            float den = __shfl(acc[4][r], lane & 48);   // from lane cl==0 of group
            float zi = 1.0f / (den + EPS);
            int row = m0 + g * 4 + r;
            size_t ga = ((size_t)(b * T + t0 + row) * H + h) * 64;
            #pragma unroll
            for (int nt = 0; nt < 4; ++nt)
                Og[ga + nt * 16 + cl] = acc[nt][r] * zi;
        }
    }
}

extern "C" void kernel_launch(void* const* d_in, const int* in_sizes, int n_in,
                              void* d_out, int out_size, void* d_ws, size_t ws_size,
                              hipStream_t stream) {
    const float* q = (const float*)d_in[0];
    const float* k = (const float*)d_in[1];
    const float* v = (const float*)d_in[2];
    float* out = (float*)d_out;

    ushort* SpartBf = (ushort*)d_ws;                                // 4.2 MB
    float*  zpart   = (float*)(SpartBf + (size_t)BH * NC * E * D);  // 128 KB
    ushort* VTg     = (ushort*)(zpart + (size_t)BH * NC * E);       // 8.4 MB
    ushort* PKg     = VTg + (size_t)BH * NC * C * D;                // 8.4 MB
    ushort* S0bf    = PKg + (size_t)BH * NC * C * E;                // 4.2 MB

    k_chunk_sums<<<BH * NC, 512, 0, stream>>>(k, v, SpartBf, zpart, VTg, PKg);
    k_scan<<<BH * 17, 256, 0, stream>>>(SpartBf, zpart, S0bf);
    k_output<<<BH * NC, 512, 0, stream>>>(q, PKg, VTg, S0bf, zpart, out);
}